// Round 9
// baseline (259.755 us; speedup 1.0000x reference)
//
#include <hip/hip_runtime.h>

using bf16x8 = __attribute__((ext_vector_type(8))) short;
using f32x4  = __attribute__((ext_vector_type(4))) float;

static constexpr int NB = 8;
static constexpr int NS = 4096;
static constexpr int NH = 16;
static constexpr int ND = 128;
static constexpr int BH = NB * NH;   // 128
static constexpr int HD = NH * ND;   // 2048

// round-to-nearest-even pack of two fp32 -> bf16x2 in a uint32
__device__ inline unsigned pack2(float a, float b) {
    unsigned ua = __float_as_uint(a), ub = __float_as_uint(b);
    ua += 0x7fffu + ((ua >> 16) & 1u);
    ub += 0x7fffu + ((ub >> 16) & 1u);
    return (ua >> 16) | (ub & 0xffff0000u);
}

// ---------------------------------------------------------------------------
// Kernel 1 (R9): global_load_lds DMA staging (bypasses VGPR load-return).
// Block = 512 thr (8 waves) on (b, head-pair hp, s-chunk c), NC=8.
// Per 16-s tile: DMA raw fp32 k,v (32 KB) -> LDS; transform (exp+pack) ->
// bf16 image img[t&1]; mma on PAIRS of images (K=32, verified intrinsic).
//   loop: B1(drain DMA t) -> transform -> B2 -> {DMA t+1, odd t: mma pair}
// LDS = raw 32 KB + img 2x16 KB = 64 KB -> 2 blocks/CU.
// ---------------------------------------------------------------------------
template <int NC>
__global__ __launch_bounds__(512, 4)
void ctx_mfma(const float* __restrict__ kk, const float* __restrict__ vv,
              float* __restrict__ pctx_t, float* __restrict__ pden) {
    constexpr int SC = NS / NC;
    constexpr int T  = SC / 16;              // even for all NC
    __shared__ __align__(16) float raw[2][16][256];                  // 32 KB
    __shared__ __align__(16) unsigned short img[2][2][4][2][128][4]; // 32 KB
    // img[buf][arr k/v][t4][hl][d][4 s]  (8B entry)

    const int blk = blockIdx.x, bhp = blk / NC, c = blk % NC;
    const int b = bhp >> 3, hp = bhp & 7;
    const int tid = threadIdx.x, l = tid & 63, wv = tid >> 6;   // 8 waves
    const int r15 = l & 15, hi = l >> 4;

    const size_t gbase = (size_t)b * NS * HD + (size_t)hp * 256;  // 2-head slice

    // ---- DMA: 32 chunks/tile (16 k-rows + 16 v-rows), 1 KB per wave-instr ----
    auto dma_tile = [&](int t) {
        const int s0 = c * SC + t * 16;
#pragma unroll
        for (int j = 0; j < 4; ++j) {
            const int ch = wv * 4 + j;
            const int arr = ch >> 4, s_i = ch & 15;
            const float* g = (arr ? vv : kk) + gbase + (size_t)(s0 + s_i) * HD + l * 4;
            __builtin_amdgcn_global_load_lds(
                (const __attribute__((address_space(1))) void*)g,
                (__attribute__((address_space(3))) void*)&raw[arr][s_i][0],
                16, 0, 0);
        }
    };

    // ---- transform: thread = (arr, 256-col). 16 scalar LDS reads (bank-free),
    //      exp (k only) + dsum, pack -> 4 uint2 img writes (bank-free). ----
    const int arr_t = tid >> 8;        // 0 = k, 1 = v
    const int dcol  = tid & 255;
    const int hl_t = dcol >> 7, d_t = dcol & 127;
    float dsum = 0.f;

    auto transform = [&](int buf) {
        float x[16];
#pragma unroll
        for (int s = 0; s < 16; ++s) x[s] = raw[arr_t][s][dcol];
        if (arr_t == 0) {
#pragma unroll
            for (int s = 0; s < 16; ++s) { x[s] = __expf(x[s]); dsum += x[s]; }
        }
#pragma unroll
        for (int t4 = 0; t4 < 4; ++t4)
            *(uint2*)&img[buf][arr_t][t4][hl_t][d_t][0] =
                make_uint2(pack2(x[4 * t4], x[4 * t4 + 1]),
                           pack2(x[4 * t4 + 2], x[4 * t4 + 3]));
    };

    // ---- mma: wave = (hm, wd, we): head hm, 64d x 64e quadrant; K=32 pair ----
    const int hm = wv >> 2, sub = wv & 3, wd = sub >> 1, we = sub & 1;
    const int ibuf = hi >> 1;          // which 16-s image holds this lane's k
    const int t4a = (2 * hi) & 3, t4b = (2 * hi + 1) & 3;

    f32x4 acc[4][4];
#pragma unroll
    for (int m = 0; m < 4; ++m)
#pragma unroll
        for (int n = 0; n < 4; ++n) acc[m][n] = (f32x4){0.f, 0.f, 0.f, 0.f};

    auto mma_pair = [&]() {
        bf16x8 af[4], bfv[4];
#pragma unroll
        for (int m = 0; m < 4; ++m) {
            const int row = 64 * wd + 16 * m + r15;
            uint2 lo = *(const uint2*)&img[ibuf][0][t4a][hm][row][0];
            uint2 h2 = *(const uint2*)&img[ibuf][0][t4b][hm][row][0];
            uint4 u = make_uint4(lo.x, lo.y, h2.x, h2.y);
            af[m] = __builtin_bit_cast(bf16x8, u);
        }
#pragma unroll
        for (int n = 0; n < 4; ++n) {
            const int row = 64 * we + 16 * n + r15;
            uint2 lo = *(const uint2*)&img[ibuf][1][t4a][hm][row][0];
            uint2 h2 = *(const uint2*)&img[ibuf][1][t4b][hm][row][0];
            uint4 u = make_uint4(lo.x, lo.y, h2.x, h2.y);
            bfv[n] = __builtin_bit_cast(bf16x8, u);
        }
#pragma unroll
        for (int m = 0; m < 4; ++m)
#pragma unroll
            for (int n = 0; n < 4; ++n)
                acc[m][n] = __builtin_amdgcn_mfma_f32_16x16x32_bf16(
                    af[m], bfv[n], acc[m][n], 0, 0, 0);
    };

    // ---- main loop ----
    dma_tile(0);
    for (int t = 0; t < T; ++t) {
        __syncthreads();                 // B1: DMA(t) drained; img[t&1] readers done
        transform(t & 1);                // raw -> img[t&1]
        __syncthreads();                 // B2: img complete; raw free
        if (t + 1 < T) dma_tile(t + 1);  // in flight across mma + next B1
        if (t & 1) mma_pair();           // consumes img[0] (t-1) + img[1] (t)
    }

    // ---- denominator: k-threads (tid<256) hold per-(hl,d) totals ----
    __syncthreads();
    if (tid < 256) {
        const int bh_g = b * 16 + hp * 2 + hl_t;
        pden[((size_t)bh_g * NC + c) * ND + d_t] = dsum;
    }

    // ---- write transposed partial context for head hm ----
    float* po = pctx_t + (((size_t)(b * 16 + hp * 2 + hm) * NC + c) << 14);
#pragma unroll
    for (int m = 0; m < 4; ++m)
#pragma unroll
        for (int n = 0; n < 4; ++n) {
            const int e  = 64 * we + 16 * n + r15;
            const int dd = 64 * wd + 16 * m + 4 * hi;
            *(f32x4*)&po[e * ND + dd] = acc[m][n];
        }
}

// ---------------------------------------------------------------------------
// Kernel 2: sum chunk partials, normalize, emit bf16 ctx_t[e][d]
// ---------------------------------------------------------------------------
__global__ void ctx_combine(const float* __restrict__ pctx_t,
                            const float* __restrict__ pden,
                            unsigned short* __restrict__ ctx_t, int nc) {
    const int gid = blockIdx.x * 256 + threadIdx.x;      // over BH*16384/2
    const size_t w = (size_t)gid * 2;
    const int bh = (int)(w >> 14);
    const int wi = (int)(w & 16383);
    const int dd = wi & 127;
    float s0 = 0.f, s1 = 0.f, dn0 = 0.f, dn1 = 0.f;
    for (int c2 = 0; c2 < nc; ++c2) {
        const float* p  = pctx_t + (((size_t)(bh * nc + c2)) << 14) + wi;
        const float* pd = pden + (size_t)(bh * nc + c2) * ND + dd;
        s0 += p[0]; s1 += p[1];
        dn0 += pd[0]; dn1 += pd[1];
    }
    *(unsigned*)&ctx_t[w] = pack2(s0 / dn0, s1 / dn1);
}

// ---------------------------------------------------------------------------
// Kernel 3: out[s][e] = (1/sum_d exp(q[s,d])) * sum_d exp(q[s,d]) * ctx[d][e]
// (unchanged)
// ---------------------------------------------------------------------------
__global__ __launch_bounds__(256, 2)
void out_mfma(const float* __restrict__ qq,
              const unsigned short* __restrict__ ctx_t,
              float* __restrict__ out) {
    __shared__ __align__(16) unsigned short cL[128][128];    // 32KB ctx_t
    __shared__ __align__(16) unsigned short qL[2][32][128];  // 16KB q tiles
    __shared__ float qd[2][32];

    const int blk = blockIdx.x, bh = blk >> 3, c = blk & 7;
    const int b = bh >> 4, h = bh & 15;
    const int tid = threadIdx.x, lane = tid & 63, wv = tid >> 6;
    const int r15 = lane & 15, hi = lane >> 4;

    {
        const unsigned short* src = ctx_t + ((size_t)bh << 14);
#pragma unroll
        for (int j = 0; j < 8; ++j) {
            const int g = tid + 256 * j;
            const int e = g >> 4, cs = g & 15;
            uint4 t4 = *(const uint4*)&src[e * 128 + cs * 8];
            *(uint4*)&cL[e][(cs ^ (e & 15)) * 8] = t4;
        }
    }

    const size_t qbase = (size_t)b * NS * HD + (size_t)h * ND;
    const int s_blk = c * 512;

    auto stageq = [&](int t, int buf) {
#pragma unroll
        for (int jj = 0; jj < 2; ++jj) {
            const int g = tid + 256 * jj;
            const int s = g >> 4, cs = g & 15;
            const float* qp = qq + qbase + (size_t)(s_blk + t * 32 + s) * HD + cs * 8;
            float x[8];
            *(float4*)&x[0] = *(const float4*)qp;
            *(float4*)&x[4] = *(const float4*)(qp + 4);
            float ps = 0.f;
            unsigned pw[4];
#pragma unroll
            for (int j2 = 0; j2 < 4; ++j2) {
                float e0 = __expf(x[2 * j2]), e1 = __expf(x[2 * j2 + 1]);
                ps += e0 + e1;
                pw[j2] = pack2(e0, e1);
            }
            ps += __shfl_xor(ps, 1);
            ps += __shfl_xor(ps, 2);
            ps += __shfl_xor(ps, 4);
            ps += __shfl_xor(ps, 8);
            *(uint4*)&qL[buf][s][(cs ^ (s & 15)) * 8] =
                make_uint4(pw[0], pw[1], pw[2], pw[3]);
            if ((lane & 15) == 0) qd[buf][s] = ps;
        }
    };

    __syncthreads();

    bf16x8 bfr[2][4];
#pragma unroll
    for (int n = 0; n < 2; ++n) {
        const int e = 32 * wv + 16 * n + r15;
#pragma unroll
        for (int ks = 0; ks < 4; ++ks) {
            const int cw = (4 * ks + hi) ^ (e & 15);
            bfr[n][ks] = *(const bf16x8*)&cL[e][cw * 8];
        }
    }

    stageq(0, 0);
    for (int t = 0; t < 16; ++t) {
        __syncthreads();
        if (t + 1 < 16) stageq(t + 1, (t + 1) & 1);
        const int buf = t & 1;

        f32x4 acc[2][2];
#pragma unroll
        for (int m = 0; m < 2; ++m)
#pragma unroll
            for (int n = 0; n < 2; ++n) acc[m][n] = (f32x4){0.f, 0.f, 0.f, 0.f};

#pragma unroll
        for (int ks = 0; ks < 4; ++ks) {
            bf16x8 af[2];
#pragma unroll
            for (int m = 0; m < 2; ++m) {
                const int s = 16 * m + r15;
                const int cw = (4 * ks + hi) ^ (s & 15);
                af[m] = *(const bf16x8*)&qL[buf][s][cw * 8];
            }
#pragma unroll
            for (int m = 0; m < 2; ++m)
#pragma unroll
                for (int n = 0; n < 2; ++n)
                    acc[m][n] = __builtin_amdgcn_mfma_f32_16x16x32_bf16(
                        af[m], bfr[n][ks], acc[m][n], 0, 0, 0);
        }

#pragma unroll
        for (int m = 0; m < 2; ++m) {
            const int sl0 = 16 * m + 4 * hi;
            const float i0 = 1.f / qd[buf][sl0];
            const float i1 = 1.f / qd[buf][sl0 + 1];
            const float i2 = 1.f / qd[buf][sl0 + 2];
            const float i3 = 1.f / qd[buf][sl0 + 3];
            const int srow = s_blk + t * 32 + sl0;
            float* ob = out + ((size_t)b * NS + srow) * HD + (size_t)h * ND;
#pragma unroll
            for (int n = 0; n < 2; ++n) {
                const int e = 32 * wv + 16 * n + r15;
                ob[0 * HD + e] = acc[m][n][0] * i0;
                ob[1 * HD + e] = acc[m][n][1] * i1;
                ob[2 * HD + e] = acc[m][n][2] * i2;
                ob[3 * HD + e] = acc[m][n][3] * i3;
            }
        }
    }
}

// ---------------------------------------------------------------------------
extern "C" void kernel_launch(void* const* d_in, const int* in_sizes, int n_in,
                              void* d_out, int out_size, void* d_ws, size_t ws_size,
                              hipStream_t stream) {
    (void)in_sizes; (void)n_in; (void)out_size;
    const float* q = (const float*)d_in[0];
    const float* k = (const float*)d_in[1];
    const float* v = (const float*)d_in[2];
    float* out = (float*)d_out;

    auto need = [](size_t nc) -> size_t {
        return 4ull * ((size_t)BH * nc * ND * ND + (size_t)BH * nc * ND) +
               2ull * (size_t)BH * ND * ND;
    };
    const int nc = (ws_size >= need(8)) ? 8
                 : (ws_size >= need(4)) ? 4
                 : (ws_size >= need(2)) ? 2 : 1;

    float* pctx_t = (float*)d_ws;
    float* pden   = pctx_t + (size_t)BH * nc * ND * ND;
    unsigned short* ctx_t = (unsigned short*)(pden + (size_t)BH * nc * ND);

    if (nc == 8)
        ctx_mfma<8><<<64 * 8, 512, 0, stream>>>(k, v, pctx_t, pden);
    else if (nc == 4)
        ctx_mfma<4><<<64 * 4, 512, 0, stream>>>(k, v, pctx_t, pden);
    else if (nc == 2)
        ctx_mfma<2><<<64 * 2, 512, 0, stream>>>(k, v, pctx_t, pden);
    else
        ctx_mfma<1><<<64 * 1, 512, 0, stream>>>(k, v, pctx_t, pden);

    ctx_combine<<<(BH * ND * ND / 2) / 256, 256, 0, stream>>>(pctx_t, pden, ctx_t, nc);

    out_mfma<<<BH * 8, 256, 0, stream>>>(q, ctx_t, out);
}

// Round 10
// 228.685 us; speedup vs baseline: 1.1359x; 1.1359x over previous
//
#include <hip/hip_runtime.h>

using bf16x8 = __attribute__((ext_vector_type(8))) short;
using f32x4  = __attribute__((ext_vector_type(4))) float;

static constexpr int NB = 8;
static constexpr int NS = 4096;
static constexpr int NH = 16;
static constexpr int ND = 128;
static constexpr int BH = NB * NH;   // 128
static constexpr int HD = NH * ND;   // 2048

// round-to-nearest-even pack of two fp32 -> bf16x2 in a uint32
__device__ inline unsigned pack2(float a, float b) {
    unsigned ua = __float_as_uint(a), ub = __float_as_uint(b);
    ua += 0x7fffu + ((ua >> 16) & 1u);
    ub += 0x7fffu + ((ub >> 16) & 1u);
    return (ua >> 16) | (ub & 0xffff0000u);
}

// ---------------------------------------------------------------------------
// Kernel 1 (R10): R9 DMA structure, partials written as bf16 (halves the
// combine-pass read volume; the read port, not HBM, is the binding resource).
// Block = 512 thr (8 waves) on (b, head-pair hp, s-chunk c), NC=8.
// ---------------------------------------------------------------------------
template <int NC>
__global__ __launch_bounds__(512, 4)
void ctx_mfma(const float* __restrict__ kk, const float* __restrict__ vv,
              unsigned short* __restrict__ pctx_t, float* __restrict__ pden) {
    constexpr int SC = NS / NC;
    constexpr int T  = SC / 16;              // even for all NC
    __shared__ __align__(16) float raw[2][16][256];                  // 32 KB
    __shared__ __align__(16) unsigned short img[2][2][4][2][128][4]; // 32 KB
    // img[buf][arr k/v][t4][hl][d][4 s]  (8B entry)

    const int blk = blockIdx.x, bhp = blk / NC, c = blk % NC;
    const int b = bhp >> 3, hp = bhp & 7;
    const int tid = threadIdx.x, l = tid & 63, wv = tid >> 6;   // 8 waves
    const int r15 = l & 15, hi = l >> 4;

    const size_t gbase = (size_t)b * NS * HD + (size_t)hp * 256;  // 2-head slice

    // ---- DMA: 32 chunks/tile (16 k-rows + 16 v-rows), 1 KB per wave-instr ----
    auto dma_tile = [&](int t) {
        const int s0 = c * SC + t * 16;
#pragma unroll
        for (int j = 0; j < 4; ++j) {
            const int ch = wv * 4 + j;
            const int arr = ch >> 4, s_i = ch & 15;
            const float* g = (arr ? vv : kk) + gbase + (size_t)(s0 + s_i) * HD + l * 4;
            __builtin_amdgcn_global_load_lds(
                (const __attribute__((address_space(1))) void*)g,
                (__attribute__((address_space(3))) void*)&raw[arr][s_i][0],
                16, 0, 0);
        }
    };

    // ---- transform: thread = (arr, 256-col). 16 scalar LDS reads (bank-free),
    //      exp (k only) + dsum, pack -> 4 uint2 img writes (bank-free). ----
    const int arr_t = tid >> 8;        // 0 = k, 1 = v
    const int dcol  = tid & 255;
    const int hl_t = dcol >> 7, d_t = dcol & 127;
    float dsum = 0.f;

    auto transform = [&](int buf) {
        float x[16];
#pragma unroll
        for (int s = 0; s < 16; ++s) x[s] = raw[arr_t][s][dcol];
        if (arr_t == 0) {
#pragma unroll
            for (int s = 0; s < 16; ++s) { x[s] = __expf(x[s]); dsum += x[s]; }
        }
#pragma unroll
        for (int t4 = 0; t4 < 4; ++t4)
            *(uint2*)&img[buf][arr_t][t4][hl_t][d_t][0] =
                make_uint2(pack2(x[4 * t4], x[4 * t4 + 1]),
                           pack2(x[4 * t4 + 2], x[4 * t4 + 3]));
    };

    // ---- mma: wave = (hm, wd, we): head hm, 64d x 64e quadrant; K=32 pair ----
    const int hm = wv >> 2, sub = wv & 3, wd = sub >> 1, we = sub & 1;
    const int ibuf = hi >> 1;          // which 16-s image holds this lane's k
    const int t4a = (2 * hi) & 3, t4b = (2 * hi + 1) & 3;

    f32x4 acc[4][4];
#pragma unroll
    for (int m = 0; m < 4; ++m)
#pragma unroll
        for (int n = 0; n < 4; ++n) acc[m][n] = (f32x4){0.f, 0.f, 0.f, 0.f};

    auto mma_pair = [&]() {
        bf16x8 af[4], bfv[4];
#pragma unroll
        for (int m = 0; m < 4; ++m) {
            const int row = 64 * wd + 16 * m + r15;
            uint2 lo = *(const uint2*)&img[ibuf][0][t4a][hm][row][0];
            uint2 h2 = *(const uint2*)&img[ibuf][0][t4b][hm][row][0];
            uint4 u = make_uint4(lo.x, lo.y, h2.x, h2.y);
            af[m] = __builtin_bit_cast(bf16x8, u);
        }
#pragma unroll
        for (int n = 0; n < 4; ++n) {
            const int row = 64 * we + 16 * n + r15;
            uint2 lo = *(const uint2*)&img[ibuf][1][t4a][hm][row][0];
            uint2 h2 = *(const uint2*)&img[ibuf][1][t4b][hm][row][0];
            uint4 u = make_uint4(lo.x, lo.y, h2.x, h2.y);
            bfv[n] = __builtin_bit_cast(bf16x8, u);
        }
#pragma unroll
        for (int m = 0; m < 4; ++m)
#pragma unroll
            for (int n = 0; n < 4; ++n)
                acc[m][n] = __builtin_amdgcn_mfma_f32_16x16x32_bf16(
                    af[m], bfv[n], acc[m][n], 0, 0, 0);
    };

    // ---- main loop ----
    dma_tile(0);
    for (int t = 0; t < T; ++t) {
        __syncthreads();                 // B1: DMA(t) drained; img[t&1] readers done
        transform(t & 1);                // raw -> img[t&1]
        __syncthreads();                 // B2: img complete; raw free
        if (t + 1 < T) dma_tile(t + 1);  // in flight across mma + next B1
        if (t & 1) mma_pair();           // consumes img[0] (t-1) + img[1] (t)
    }

    // ---- denominator: k-threads (tid<256) hold per-(hl,d) totals ----
    __syncthreads();
    if (tid < 256) {
        const int bh_g = b * 16 + hp * 2 + hl_t;
        pden[((size_t)bh_g * NC + c) * ND + d_t] = dsum;
    }

    // ---- write transposed partial context for head hm (bf16) ----
    unsigned short* po =
        pctx_t + (((size_t)(b * 16 + hp * 2 + hm) * NC + c) << 14);
#pragma unroll
    for (int m = 0; m < 4; ++m)
#pragma unroll
        for (int n = 0; n < 4; ++n) {
            const int e  = 64 * we + 16 * n + r15;
            const int dd = 64 * wd + 16 * m + 4 * hi;
            *(uint2*)&po[e * ND + dd] =
                make_uint2(pack2(acc[m][n][0], acc[m][n][1]),
                           pack2(acc[m][n][2], acc[m][n][3]));
        }
}

// ---------------------------------------------------------------------------
// Kernel 2: sum bf16 chunk partials, normalize, emit bf16 ctx_t[e][d]
// ---------------------------------------------------------------------------
__global__ void ctx_combine(const unsigned short* __restrict__ pctx_t,
                            const float* __restrict__ pden,
                            unsigned short* __restrict__ ctx_t, int nc) {
    const int gid = blockIdx.x * 256 + threadIdx.x;      // over BH*16384/2
    const size_t w = (size_t)gid * 2;
    const int bh = (int)(w >> 14);
    const int wi = (int)(w & 16383);                     // even
    const int dd = wi & 127;
    float s0 = 0.f, s1 = 0.f, dn0 = 0.f, dn1 = 0.f;
    for (int c2 = 0; c2 < nc; ++c2) {
        const unsigned u =
            *(const unsigned*)&pctx_t[(((size_t)(bh * nc + c2)) << 14) + wi];
        s0 += __uint_as_float(u << 16);
        s1 += __uint_as_float(u & 0xffff0000u);
        const float* pd = pden + (size_t)(bh * nc + c2) * ND + dd;
        dn0 += pd[0]; dn1 += pd[1];
    }
    *(unsigned*)&ctx_t[w] = pack2(s0 / dn0, s1 / dn1);
}

// ---------------------------------------------------------------------------
// Kernel 3: out[s][e] = (1/sum_d exp(q[s,d])) * sum_d exp(q[s,d]) * ctx[d][e]
// R10: 4 blocks per bh (1024 s each) -> halves redundant ctx_t reads.
// ---------------------------------------------------------------------------
__global__ __launch_bounds__(256, 2)
void out_mfma(const float* __restrict__ qq,
              const unsigned short* __restrict__ ctx_t,
              float* __restrict__ out) {
    __shared__ __align__(16) unsigned short cL[128][128];    // 32KB ctx_t
    __shared__ __align__(16) unsigned short qL[2][32][128];  // 16KB q tiles
    __shared__ float qd[2][32];

    const int blk = blockIdx.x, bh = blk >> 2, c = blk & 3;
    const int b = bh >> 4, h = bh & 15;
    const int tid = threadIdx.x, lane = tid & 63, wv = tid >> 6;
    const int r15 = lane & 15, hi = lane >> 4;

    {
        const unsigned short* src = ctx_t + ((size_t)bh << 14);
#pragma unroll
        for (int j = 0; j < 8; ++j) {
            const int g = tid + 256 * j;
            const int e = g >> 4, cs = g & 15;
            uint4 t4 = *(const uint4*)&src[e * 128 + cs * 8];
            *(uint4*)&cL[e][(cs ^ (e & 15)) * 8] = t4;
        }
    }

    const size_t qbase = (size_t)b * NS * HD + (size_t)h * ND;
    const int s_blk = c * 1024;

    auto stageq = [&](int t, int buf) {
#pragma unroll
        for (int jj = 0; jj < 2; ++jj) {
            const int g = tid + 256 * jj;
            const int s = g >> 4, cs = g & 15;
            const float* qp = qq + qbase + (size_t)(s_blk + t * 32 + s) * HD + cs * 8;
            float x[8];
            *(float4*)&x[0] = *(const float4*)qp;
            *(float4*)&x[4] = *(const float4*)(qp + 4);
            float ps = 0.f;
            unsigned pw[4];
#pragma unroll
            for (int j2 = 0; j2 < 4; ++j2) {
                float e0 = __expf(x[2 * j2]), e1 = __expf(x[2 * j2 + 1]);
                ps += e0 + e1;
                pw[j2] = pack2(e0, e1);
            }
            ps += __shfl_xor(ps, 1);
            ps += __shfl_xor(ps, 2);
            ps += __shfl_xor(ps, 4);
            ps += __shfl_xor(ps, 8);
            *(uint4*)&qL[buf][s][(cs ^ (s & 15)) * 8] =
                make_uint4(pw[0], pw[1], pw[2], pw[3]);
            if ((lane & 15) == 0) qd[buf][s] = ps;
        }
    };

    __syncthreads();

    bf16x8 bfr[2][4];
#pragma unroll
    for (int n = 0; n < 2; ++n) {
        const int e = 32 * wv + 16 * n + r15;
#pragma unroll
        for (int ks = 0; ks < 4; ++ks) {
            const int cw = (4 * ks + hi) ^ (e & 15);
            bfr[n][ks] = *(const bf16x8*)&cL[e][cw * 8];
        }
    }

    stageq(0, 0);
    for (int t = 0; t < 32; ++t) {
        __syncthreads();
        if (t + 1 < 32) stageq(t + 1, (t + 1) & 1);
        const int buf = t & 1;

        f32x4 acc[2][2];
#pragma unroll
        for (int m = 0; m < 2; ++m)
#pragma unroll
            for (int n = 0; n < 2; ++n) acc[m][n] = (f32x4){0.f, 0.f, 0.f, 0.f};

#pragma unroll
        for (int ks = 0; ks < 4; ++ks) {
            bf16x8 af[2];
#pragma unroll
            for (int m = 0; m < 2; ++m) {
                const int s = 16 * m + r15;
                const int cw = (4 * ks + hi) ^ (s & 15);
                af[m] = *(const bf16x8*)&qL[buf][s][cw * 8];
            }
#pragma unroll
            for (int m = 0; m < 2; ++m)
#pragma unroll
                for (int n = 0; n < 2; ++n)
                    acc[m][n] = __builtin_amdgcn_mfma_f32_16x16x32_bf16(
                        af[m], bfr[n][ks], acc[m][n], 0, 0, 0);
        }

#pragma unroll
        for (int m = 0; m < 2; ++m) {
            const int sl0 = 16 * m + 4 * hi;
            const float i0 = 1.f / qd[buf][sl0];
            const float i1 = 1.f / qd[buf][sl0 + 1];
            const float i2 = 1.f / qd[buf][sl0 + 2];
            const float i3 = 1.f / qd[buf][sl0 + 3];
            const int srow = s_blk + t * 32 + sl0;
            float* ob = out + ((size_t)b * NS + srow) * HD + (size_t)h * ND;
#pragma unroll
            for (int n = 0; n < 2; ++n) {
                const int e = 32 * wv + 16 * n + r15;
                ob[0 * HD + e] = acc[m][n][0] * i0;
                ob[1 * HD + e] = acc[m][n][1] * i1;
                ob[2 * HD + e] = acc[m][n][2] * i2;
                ob[3 * HD + e] = acc[m][n][3] * i3;
            }
        }
    }
}

// ---------------------------------------------------------------------------
extern "C" void kernel_launch(void* const* d_in, const int* in_sizes, int n_in,
                              void* d_out, int out_size, void* d_ws, size_t ws_size,
                              hipStream_t stream) {
    (void)in_sizes; (void)n_in; (void)out_size;
    const float* q = (const float*)d_in[0];
    const float* k = (const float*)d_in[1];
    const float* v = (const float*)d_in[2];
    float* out = (float*)d_out;

    auto need = [](size_t nc) -> size_t {
        return 2ull * (size_t)BH * nc * ND * ND     // pctx bf16
             + 4ull * (size_t)BH * nc * ND          // pden fp32
             + 2ull * (size_t)BH * ND * ND;         // ctx_t bf16
    };
    const int nc = (ws_size >= need(8)) ? 8
                 : (ws_size >= need(4)) ? 4
                 : (ws_size >= need(2)) ? 2 : 1;

    unsigned short* pctx = (unsigned short*)d_ws;
    float* pden = (float*)(pctx + (size_t)BH * nc * ND * ND);
    unsigned short* ctx_t = (unsigned short*)(pden + (size_t)BH * nc * ND);

    if (nc == 8)
        ctx_mfma<8><<<64 * 8, 512, 0, stream>>>(k, v, pctx, pden);
    else if (nc == 4)
        ctx_mfma<4><<<64 * 4, 512, 0, stream>>>(k, v, pctx, pden);
    else if (nc == 2)
        ctx_mfma<2><<<64 * 2, 512, 0, stream>>>(k, v, pctx, pden);
    else
        ctx_mfma<1><<<64 * 1, 512, 0, stream>>>(k, v, pctx, pden);

    ctx_combine<<<(BH * ND * ND / 2) / 256, 256, 0, stream>>>(pctx, pden, ctx_t, nc);

    out_mfma<<<BH * 4, 256, 0, stream>>>(q, ctx_t, out);
}